// Round 7
// baseline (915.378 us; speedup 1.0000x reference)
//
#include <hip/hip_runtime.h>
#include <cstdint>
#include <cstddef>

#define NND   128
#define FEATD 1024
#define MSGD  256
#define LHD   512
#define CLSD  600
#define LDST  264   // padded LDS stride for tier1/2 kernels (f32-edge path)

typedef __bf16 bf16_t;
typedef bf16_t bf16x8 __attribute__((ext_vector_type(8)));
typedef float  f32x4  __attribute__((ext_vector_type(4)));
typedef unsigned short u16;
typedef u16 u16x8 __attribute__((ext_vector_type(8)));
typedef u16 u16x4 __attribute__((ext_vector_type(4)));

static __device__ __forceinline__ float bf2f(u16 u) {
  union { unsigned u; float f; } x; x.u = ((unsigned)u) << 16; return x.f;
}
static __device__ __forceinline__ u16 f2bf(float f) {
  union { float f; unsigned u; } x; x.f = f;
  return (u16)((x.u + 0x7fffu + ((x.u >> 16) & 1u)) >> 16);  // RNE
}
static __device__ __forceinline__ f32x4 mfma16(u16x8 a, u16x8 b, f32x4 c) {
  return __builtin_amdgcn_mfma_f32_16x16x32_bf16(
      __builtin_bit_cast(bf16x8, a), __builtin_bit_cast(bf16x8, b), c, 0, 0, 0);
}
static __device__ __forceinline__ f32x4 zero4() {
  f32x4 v; v[0] = 0.f; v[1] = 0.f; v[2] = 0.f; v[3] = 0.f; return v;
}
static __device__ __forceinline__ float sigm(float x) { return 1.0f / (1.0f + expf(-x)); }

// async 16B global -> LDS (explicit addrspace casts; dest must be wave-uniform base, HW adds lane*16)
#define GLD16(gsrc, ldst)                                                      \
  __builtin_amdgcn_global_load_lds(                                            \
      (const __attribute__((address_space(1))) unsigned int*)(gsrc),           \
      (__attribute__((address_space(3))) unsigned int*)(ldst), 16, 0, 0)

// ---------------------------------------------------------------- weight cvt f32->bf16
__global__ void k_cvt(const float* __restrict__ src, u16* __restrict__ dst, int n) {
  int i = (blockIdx.x * 256 + threadIdx.x) * 4;
  if (i + 3 < n) {
    float4 f = *(const float4*)(src + i);
    u16x4 o; o[0] = f2bf(f.x); o[1] = f2bf(f.y); o[2] = f2bf(f.z); o[3] = f2bf(f.w);
    *(u16x4*)(dst + i) = o;
  }
}

// ---------------------------------------------------------------- edge f32 -> bf16 (grid-stride stream)
__global__ __launch_bounds__(256) void k_cvt_edge(const float* __restrict__ src,
                                                  u16* __restrict__ dst, long n) {
  long i = ((long)blockIdx.x * 256 + threadIdx.x) * 8;
  const long stride = (long)gridDim.x * 256 * 8;
  for (; i + 7 < n; i += stride) {
    float4 a = *(const float4*)(src + i);
    float4 b = *(const float4*)(src + i + 4);
    u16x8 o;
    o[0] = f2bf(a.x); o[1] = f2bf(a.y); o[2] = f2bf(a.z); o[3] = f2bf(a.w);
    o[4] = f2bf(b.x); o[5] = f2bf(b.y); o[6] = f2bf(b.z); o[7] = f2bf(b.w);
    *(u16x8*)(dst + i) = o;
  }
}

// ---------------------------------------------------------------- W_comb = W_me @ W_er (tier2 only)
__global__ __launch_bounds__(256) void k_comb(const float* __restrict__ Wm,
                                              const float* __restrict__ Wer,
                                              const float* __restrict__ b_er,
                                              const float* __restrict__ b_m,
                                              u16* __restrict__ WcombB,
                                              float* __restrict__ bcomb) {
  const int m = blockIdx.x >> 2, ch = blockIdx.x & 3;
  const int d = ch * 256 + threadIdx.x;
  float s = 0.f;
  for (int k = 0; k < 256; ++k)
    s += Wm[(size_t)m * 512 + 256 + k] * Wer[(size_t)k * FEATD + d];
  WcombB[(size_t)m * FEATD + d] = f2bf(s);
  if (ch == 0 && threadIdx.x == 0) {
    float bb2 = b_m[m];
    for (int k = 0; k < 256; ++k) bb2 += Wm[(size_t)m * 512 + 256 + k] * b_er[k];
    bcomb[m] = bb2;
  }
}

// ---------------------------------------------------------------- S1: h (f32) + msg_h (bf16)
__global__ __launch_bounds__(256) void s1_hmsg(const float* __restrict__ node,
                                               const float* __restrict__ Wnr,
                                               const float* __restrict__ bnr,
                                               const float* __restrict__ Wm,
                                               float* __restrict__ h32,
                                               u16* __restrict__ msghB) {
  __shared__ float nrow[FEATD];
  __shared__ float hrow[MSGD];
  const int r = blockIdx.x;
  const int t = threadIdx.x;
  *(float4*)(&nrow[t * 4]) = *(const float4*)(node + (size_t)r * FEATD + t * 4);
  __syncthreads();
  float acc = bnr[t];
  for (int d = 0; d < FEATD; ++d) acc += nrow[d] * Wnr[(size_t)t * FEATD + d];
  h32[(size_t)r * MSGD + t] = acc;
  hrow[t] = acc;
  __syncthreads();
  float mh = 0.f;
  for (int k = 0; k < MSGD; ++k) mh += hrow[k] * Wm[(size_t)t * 2 * MSGD + k];
  msghB[(size_t)r * MSGD + t] = f2bf(mh);
}

// ---------------------------------------------------------------- tier0 main: bf16 edge + global_load_lds + dbuf
// LDS tiles are LINEAR [64][256]u16 (512B rows) with XOR swizzle: phys_byte = row*512 + (bo ^ ((row&7)<<4)).
// Staging pre-applies the inverse (== same) swizzle on the per-lane GLOBAL source address (rule #21).
__global__ __launch_bounds__(512, 4) void k_main_bf(
    const u16* __restrict__ edgeB, const u16* __restrict__ Wer, const u16* __restrict__ Wm,
    const u16* __restrict__ Wl1, const float* __restrict__ b_er, const float* __restrict__ b_m,
    const float* __restrict__ b_l1, const float* __restrict__ W_l2, const float* __restrict__ b_l2,
    const u16* __restrict__ msgh, u16* __restrict__ M0g, float* __restrict__ pa_out) {
  __shared__ __align__(16) u16 lsS0[64 * 256];   // stage buf0 -> later e-tile
  __shared__ __align__(16) u16 lsS1[64 * 256];   // stage buf1 -> later m1-tile
  __shared__ float lsPA[8][64];
  __shared__ float lsSig[64];

  const int tid = threadIdx.x, lane = tid & 63, wave = tid >> 6;  // 8 waves
  const int lh = lane & 15, lq = lane >> 4;
  const int base = blockIdx.x * 64;
  const int bb = base >> 14, vv = (base >> 7) & 127, w0 = base & 127;

  // swizzled element pointer (bo = logical byte offset within 512B row)
  auto ELP = [&](u16* b, int row, int bo) -> u16* {
    return (u16*)((char*)b + row * 512 + (bo ^ ((row & 7) << 4)));
  };
  // stage kc-chunk (cols kc*256..+255 of each of 64 rows) into pb
  auto STAGE = [&](int kc, int pb) {
    char* bufc = (char*)(pb ? lsS1 : lsS0);
#pragma unroll
    for (int i = 0; i < 4; ++i) {
      int r = i * 16 + (tid >> 5);
      int sb = (((tid & 31) * 16) ^ (((tid >> 5) & 7) << 4));  // pre-swizzled source byte
      const char* gsrc = (const char*)edgeB + ((size_t)(base + r) * 2048) + kc * 512 + sb;
      char* ldst = bufc + i * 8192 + wave * 1024;              // wave-uniform; HW adds lane*16
      GLD16(gsrc, ldst);
    }
  };

  f32x4 acc[4][4];

  // ---------------- Phase 0: e = edge @ Wer^T + b_er ----------------
#pragma unroll
  for (int m = 0; m < 4; ++m)
#pragma unroll
    for (int t = 0; t < 2; ++t) acc[m][t] = zero4();
  STAGE(0, 0);
  __syncthreads();
  for (int kc = 0; kc < 4; ++kc) {
    if (kc < 3) STAGE(kc + 1, (kc + 1) & 1);        // async prefetch overlaps MFMA below
    u16* sb = (kc & 1) ? lsS1 : lsS0;
    const int kg0 = kc * 256;
#pragma unroll
    for (int ks = 0; ks < 8; ++ks) {
      u16x8 afr[4];
#pragma unroll
      for (int m = 0; m < 4; ++m)
        afr[m] = *(const u16x8*)ELP(sb, 16 * m + lh, ks * 64 + lq * 16);
      const int kg = kg0 + ks * 32 + lq * 8;
#pragma unroll
      for (int t = 0; t < 2; ++t) {
        int col = wave * 32 + t * 16 + lh;
        u16x8 bfr = *(const u16x8*)(Wer + (size_t)col * FEATD + kg);
#pragma unroll
        for (int m = 0; m < 4; ++m) acc[m][t] = mfma16(afr[m], bfr, acc[m][t]);
      }
    }
    __syncthreads();                                 // drains prefetch too (vmcnt at barrier)
  }
  // e-out into lsS0 (kc=2 data consumed two barriers ago)
#pragma unroll
  for (int t = 0; t < 2; ++t) {
    int col = wave * 32 + t * 16 + lh;
    float be = b_er[col];
#pragma unroll
    for (int m = 0; m < 4; ++m)
#pragma unroll
      for (int j = 0; j < 4; ++j)
        *ELP(lsS0, 16 * m + 4 * lq + j, col * 2) = f2bf(acc[m][t][j] + be);
  }
  __syncthreads();

  // ---------------- Phase A: sig1 ----------------
  float prow[4][4];
#pragma unroll
  for (int m = 0; m < 4; ++m)
#pragma unroll
    for (int j = 0; j < 4; ++j) prow[m][j] = 0.f;
#pragma unroll
  for (int m = 0; m < 4; ++m)
#pragma unroll
    for (int t = 0; t < 4; ++t) acc[m][t] = zero4();
#pragma unroll
  for (int ks = 0; ks < 8; ++ks) {
    u16x8 afr[4];
#pragma unroll
    for (int m = 0; m < 4; ++m)
      afr[m] = *(const u16x8*)ELP(lsS0, 16 * m + lh, ks * 64 + lq * 16);
    const int kg = ks * 32 + lq * 8;
#pragma unroll
    for (int t = 0; t < 4; ++t) {
      int col = wave * 64 + t * 16 + lh;
      u16x8 bfr = *(const u16x8*)(Wl1 + (size_t)col * MSGD + kg);
#pragma unroll
      for (int m = 0; m < 4; ++m) acc[m][t] = mfma16(afr[m], bfr, acc[m][t]);
    }
  }
#pragma unroll
  for (int t = 0; t < 4; ++t) {
    int col = wave * 64 + t * 16 + lh;
    float bl = b_l1[col], wl = W_l2[col];
#pragma unroll
    for (int m = 0; m < 4; ++m)
#pragma unroll
      for (int j = 0; j < 4; ++j) prow[m][j] += fmaxf(acc[m][t][j] + bl, 0.f) * wl;
  }
#pragma unroll
  for (int off = 1; off < 16; off <<= 1)
#pragma unroll
    for (int m = 0; m < 4; ++m)
#pragma unroll
      for (int j = 0; j < 4; ++j) prow[m][j] += __shfl_xor(prow[m][j], off, 64);
  if (lh == 0) {
#pragma unroll
    for (int m = 0; m < 4; ++m)
#pragma unroll
      for (int j = 0; j < 4; ++j) lsPA[wave][16 * m + 4 * lq + j] = prow[m][j];
  }
  __syncthreads();
  if (tid < 64) {
    float pa1 = b_l2[0];
#pragma unroll
    for (int g = 0; g < 8; ++g) pa1 += lsPA[g][tid];
    lsSig[tid] = sigm(pa1);
  }

  // ---------------- Phase B: M0 = relu(msg_h + e@Wme^T + b_m) -> lsS1 ----------------
#pragma unroll
  for (int m = 0; m < 4; ++m)
#pragma unroll
    for (int t = 0; t < 2; ++t) acc[m][t] = zero4();
#pragma unroll
  for (int ks = 0; ks < 8; ++ks) {
    u16x8 afr[4];
#pragma unroll
    for (int m = 0; m < 4; ++m)
      afr[m] = *(const u16x8*)ELP(lsS0, 16 * m + lh, ks * 64 + lq * 16);
    const int kg = ks * 32 + lq * 8;
#pragma unroll
    for (int t = 0; t < 2; ++t) {
      int col = wave * 32 + t * 16 + lh;
      u16x8 bfr = *(const u16x8*)(Wm + (size_t)col * 512 + 256 + kg);  // W_me
#pragma unroll
      for (int m = 0; m < 4; ++m) acc[m][t] = mfma16(afr[m], bfr, acc[m][t]);
    }
  }
#pragma unroll
  for (int t = 0; t < 2; ++t) {
    int col = wave * 32 + t * 16 + lh;
    float bm = b_m[col];
#pragma unroll
    for (int m = 0; m < 4; ++m)
#pragma unroll
      for (int j = 0; j < 4; ++j) {
        int row = 16 * m + 4 * lq + j;
        float mh = bf2f(msgh[(size_t)(bb * NND + w0 + row) * MSGD + col]);  // global, L2-hot
        *ELP(lsS1, row, col * 2) = f2bf(fmaxf(acc[m][t][j] + bm + mh, 0.f));
      }
  }
  __syncthreads();
  // M0 -> global; prescale in place: m1 = sig1 * M0
#pragma unroll
  for (int i = 0; i < 4; ++i) {
    int idx = tid + i * 512;
    int row = idx >> 5;
    int c8 = (idx & 31) << 3;
    u16x8 m0v = *(const u16x8*)ELP(lsS1, row, c8 * 2);
    if (M0g) *(u16x8*)(M0g + (size_t)(base + row) * MSGD + c8) = m0v;
    float s = lsSig[row];
    u16x8 sc;
#pragma unroll
    for (int j = 0; j < 8; ++j) sc[j] = f2bf(bf2f(m0v[j]) * s);
    *(u16x8*)ELP(lsS1, row, c8 * 2) = sc;
  }
  __syncthreads();

  // ---------------- Phase C: pred_adj2 (scatter transposed, f32) ----------------
#pragma unroll
  for (int m = 0; m < 4; ++m)
#pragma unroll
    for (int j = 0; j < 4; ++j) prow[m][j] = 0.f;
#pragma unroll
  for (int m = 0; m < 4; ++m)
#pragma unroll
    for (int t = 0; t < 4; ++t) acc[m][t] = zero4();
#pragma unroll
  for (int ks = 0; ks < 8; ++ks) {
    u16x8 afr[4];
#pragma unroll
    for (int m = 0; m < 4; ++m)
      afr[m] = *(const u16x8*)ELP(lsS1, 16 * m + lh, ks * 64 + lq * 16);
    const int kg = ks * 32 + lq * 8;
#pragma unroll
    for (int t = 0; t < 4; ++t) {
      int col = wave * 64 + t * 16 + lh;
      u16x8 bfr = *(const u16x8*)(Wl1 + (size_t)col * MSGD + kg);
#pragma unroll
      for (int m = 0; m < 4; ++m) acc[m][t] = mfma16(afr[m], bfr, acc[m][t]);
    }
  }
#pragma unroll
  for (int t = 0; t < 4; ++t) {
    int col = wave * 64 + t * 16 + lh;
    float bl = b_l1[col], wl = W_l2[col];
#pragma unroll
    for (int m = 0; m < 4; ++m)
#pragma unroll
      for (int j = 0; j < 4; ++j) prow[m][j] += fmaxf(acc[m][t][j] + bl, 0.f) * wl;
  }
#pragma unroll
  for (int off = 1; off < 16; off <<= 1)
#pragma unroll
    for (int m = 0; m < 4; ++m)
#pragma unroll
      for (int j = 0; j < 4; ++j) prow[m][j] += __shfl_xor(prow[m][j], off, 64);
  if (lh == 0) {
#pragma unroll
    for (int m = 0; m < 4; ++m)
#pragma unroll
      for (int j = 0; j < 4; ++j) lsPA[wave][16 * m + 4 * lq + j] = prow[m][j];
  }
  __syncthreads();
  if (tid < 64) {
    float q = b_l2[0];
#pragma unroll
    for (int g = 0; g < 8; ++g) q += lsPA[g][tid];
    size_t o = ((size_t)bb * NND + (w0 + tid)) * NND + vv;
    pa_out[o] = q;
  }
}

// ---------------------------------------------------------------- tier1/2 main: f32 edge, reg staging (R6)
__global__ __launch_bounds__(512, 4) void k_main_f32(
    const float* __restrict__ edge, const u16* __restrict__ Wer, const u16* __restrict__ Wm,
    const u16* __restrict__ Wl1, const float* __restrict__ b_er, const float* __restrict__ b_m,
    const float* __restrict__ b_l1, const float* __restrict__ W_l2, const float* __restrict__ b_l2,
    const u16* __restrict__ msgh, u16* __restrict__ M0g, float* __restrict__ pa_out) {
  __shared__ __align__(16) u16 lsE[64][LDST];
  __shared__ __align__(16) u16 lsM[64][LDST];
  __shared__ float lsPA[8][64];
  __shared__ float lsSig[64];

  const int tid = threadIdx.x, lane = tid & 63, wave = tid >> 6;
  const int lh = lane & 15, lq = lane >> 4;
  const int base = blockIdx.x * 64;
  const int bb = base >> 14;
  const int vv = (base >> 7) & 127;
  const int w0 = base & 127;

  f32x4 acc[4][4];

#pragma unroll
  for (int m = 0; m < 4; ++m)
#pragma unroll
    for (int t = 0; t < 2; ++t) acc[m][t] = zero4();
  for (int kc = 0; kc < 4; ++kc) {
#pragma unroll
    for (int i = 0; i < 8; ++i) {
      int idx = tid + i * 512;
      int row = idx >> 6;
      int c4 = (idx & 63) << 2;
      float4 f = *(const float4*)(edge + (size_t)(base + row) * FEATD + kc * 256 + c4);
      u16x4 o; o[0] = f2bf(f.x); o[1] = f2bf(f.y); o[2] = f2bf(f.z); o[3] = f2bf(f.w);
      *(u16x4*)(&lsE[row][c4]) = o;
    }
    __syncthreads();
#pragma unroll
    for (int ks = 0; ks < 8; ++ks) {
      u16x8 afr[4];
#pragma unroll
      for (int m = 0; m < 4; ++m) afr[m] = *(const u16x8*)(&lsE[16 * m + lh][ks * 32 + lq * 8]);
      const int kg = kc * 256 + ks * 32 + lq * 8;
#pragma unroll
      for (int t = 0; t < 2; ++t) {
        int col = wave * 32 + t * 16 + lh;
        u16x8 bfr = *(const u16x8*)(Wer + (size_t)col * FEATD + kg);
#pragma unroll
        for (int m = 0; m < 4; ++m) acc[m][t] = mfma16(afr[m], bfr, acc[m][t]);
      }
    }
    __syncthreads();
  }
#pragma unroll
  for (int t = 0; t < 2; ++t) {
    int col = wave * 32 + t * 16 + lh;
    float be = b_er[col];
#pragma unroll
    for (int m = 0; m < 4; ++m)
#pragma unroll
      for (int j = 0; j < 4; ++j)
        lsE[16 * m + 4 * lq + j][col] = f2bf(acc[m][t][j] + be);
  }
  __syncthreads();

  float prow[4][4];
#pragma unroll
  for (int m = 0; m < 4; ++m)
#pragma unroll
    for (int j = 0; j < 4; ++j) prow[m][j] = 0.f;
#pragma unroll
  for (int m = 0; m < 4; ++m)
#pragma unroll
    for (int t = 0; t < 4; ++t) acc[m][t] = zero4();
#pragma unroll
  for (int ks = 0; ks < 8; ++ks) {
    u16x8 afr[4];
#pragma unroll
    for (int m = 0; m < 4; ++m) afr[m] = *(const u16x8*)(&lsE[16 * m + lh][ks * 32 + lq * 8]);
    const int kg = ks * 32 + lq * 8;
#pragma unroll
    for (int t = 0; t < 4; ++t) {
      int col = wave * 64 + t * 16 + lh;
      u16x8 bfr = *(const u16x8*)(Wl1 + (size_t)col * MSGD + kg);
#pragma unroll
      for (int m = 0; m < 4; ++m) acc[m][t] = mfma16(afr[m], bfr, acc[m][t]);
    }
  }
#pragma unroll
  for (int t = 0; t < 4; ++t) {
    int col = wave * 64 + t * 16 + lh;
    float bl = b_l1[col], wl = W_l2[col];
#pragma unroll
    for (int m = 0; m < 4; ++m)
#pragma unroll
      for (int j = 0; j < 4; ++j) prow[m][j] += fmaxf(acc[m][t][j] + bl, 0.f) * wl;
  }
#pragma unroll
  for (int off = 1; off < 16; off <<= 1)
#pragma unroll
    for (int m = 0; m < 4; ++m)
#pragma unroll
      for (int j = 0; j < 4; ++j) prow[m][j] += __shfl_xor(prow[m][j], off, 64);
  if (lh == 0) {
#pragma unroll
    for (int m = 0; m < 4; ++m)
#pragma unroll
      for (int j = 0; j < 4; ++j) lsPA[wave][16 * m + 4 * lq + j] = prow[m][j];
  }
  __syncthreads();
  if (tid < 64) {
    float pa1 = b_l2[0];
#pragma unroll
    for (int g = 0; g < 8; ++g) pa1 += lsPA[g][tid];
    lsSig[tid] = sigm(pa1);
  }
#pragma unroll
  for (int i = 0; i < 4; ++i) {
    int idx = tid + i * 512;
    int row = idx >> 5;
    int c8 = (idx & 31) << 3;
    *(u16x8*)(&lsM[row][c8]) =
        *(const u16x8*)(msgh + (size_t)(bb * NND + w0 + row) * MSGD + c8);
  }
  __syncthreads();

#pragma unroll
  for (int m = 0; m < 4; ++m)
#pragma unroll
    for (int t = 0; t < 2; ++t) acc[m][t] = zero4();
#pragma unroll
  for (int ks = 0; ks < 8; ++ks) {
    u16x8 afr[4];
#pragma unroll
    for (int m = 0; m < 4; ++m) afr[m] = *(const u16x8*)(&lsE[16 * m + lh][ks * 32 + lq * 8]);
    const int kg = ks * 32 + lq * 8;
#pragma unroll
    for (int t = 0; t < 2; ++t) {
      int col = wave * 32 + t * 16 + lh;
      u16x8 bfr = *(const u16x8*)(Wm + (size_t)col * 512 + 256 + kg);
#pragma unroll
      for (int m = 0; m < 4; ++m) acc[m][t] = mfma16(afr[m], bfr, acc[m][t]);
    }
  }
#pragma unroll
  for (int t = 0; t < 2; ++t) {
    int col = wave * 32 + t * 16 + lh;
    float bm = b_m[col];
#pragma unroll
    for (int m = 0; m < 4; ++m)
#pragma unroll
      for (int j = 0; j < 4; ++j) {
        int row = 16 * m + 4 * lq + j;
        float mh = bf2f(lsM[row][col]);
        lsM[row][col] = f2bf(fmaxf(acc[m][t][j] + bm + mh, 0.f));
      }
  }
  __syncthreads();
#pragma unroll
  for (int i = 0; i < 4; ++i) {
    int idx = tid + i * 512;
    int row = idx >> 5;
    int c8 = (idx & 31) << 3;
    u16x8 m0v = *(const u16x8*)(&lsM[row][c8]);
    if (M0g) *(u16x8*)(M0g + (size_t)(base + row) * MSGD + c8) = m0v;
    float s = lsSig[row];
    u16x8 sc;
#pragma unroll
    for (int j = 0; j < 8; ++j) sc[j] = f2bf(bf2f(m0v[j]) * s);
    *(u16x8*)(&lsM[row][c8]) = sc;
  }
  __syncthreads();

#pragma unroll
  for (int m = 0; m < 4; ++m)
#pragma unroll
    for (int j = 0; j < 4; ++j) prow[m][j] = 0.f;
#pragma unroll
  for (int m = 0; m < 4; ++m)
#pragma unroll
    for (int t = 0; t < 4; ++t) acc[m][t] = zero4();
#pragma unroll
  for (int ks = 0; ks < 8; ++ks) {
    u16x8 afr[4];
#pragma unroll
    for (int m = 0; m < 4; ++m) afr[m] = *(const u16x8*)(&lsM[16 * m + lh][ks * 32 + lq * 8]);
    const int kg = ks * 32 + lq * 8;
#pragma unroll
    for (int t = 0; t < 4; ++t) {
      int col = wave * 64 + t * 16 + lh;
      u16x8 bfr = *(const u16x8*)(Wl1 + (size_t)col * MSGD + kg);
#pragma unroll
      for (int m = 0; m < 4; ++m) acc[m][t] = mfma16(afr[m], bfr, acc[m][t]);
    }
  }
#pragma unroll
  for (int t = 0; t < 4; ++t) {
    int col = wave * 64 + t * 16 + lh;
    float bl = b_l1[col], wl = W_l2[col];
#pragma unroll
    for (int m = 0; m < 4; ++m)
#pragma unroll
      for (int j = 0; j < 4; ++j) prow[m][j] += fmaxf(acc[m][t][j] + bl, 0.f) * wl;
  }
#pragma unroll
  for (int off = 1; off < 16; off <<= 1)
#pragma unroll
    for (int m = 0; m < 4; ++m)
#pragma unroll
      for (int j = 0; j < 4; ++j) prow[m][j] += __shfl_xor(prow[m][j], off, 64);
  if (lh == 0) {
#pragma unroll
    for (int m = 0; m < 4; ++m)
#pragma unroll
      for (int j = 0; j < 4; ++j) lsPA[wave][16 * m + 4 * lq + j] = prow[m][j];
  }
  __syncthreads();
  if (tid < 64) {
    float q = b_l2[0];
#pragma unroll
    for (int g = 0; g < 8; ++g) q += lsPA[g][tid];
    size_t o = ((size_t)bb * NND + (w0 + tid)) * NND + vv;
    pa_out[o] = q;
  }
}

// ---------------------------------------------------------------- m_sum from stored M0
__global__ __launch_bounds__(256) void k_msum_lite(const u16* __restrict__ M0g,
                                                   const float* __restrict__ qv,
                                                   float* __restrict__ msum) {
  __shared__ float sig[128];
  const int bv = blockIdx.x, tid = threadIdx.x;
  if (tid < 128) sig[tid] = sigm(qv[(size_t)bv * NND + tid]);
  __syncthreads();
  const u16* p = M0g + (size_t)bv * NND * MSGD + tid;
  float a = 0.f;
#pragma unroll 8
  for (int w = 0; w < 128; ++w) a += sig[w] * bf2f(p[(size_t)w * MSGD]);
  msum[(size_t)bv * MSGD + tid] = a;
}

// ---------------------------------------------------------------- tier2 m_sum: recompute via W_comb
__global__ __launch_bounds__(256, 2) void k_msum2(
    const float* __restrict__ edge, const u16* __restrict__ Wcomb,
    const float* __restrict__ bcomb, const u16* __restrict__ msgh,
    const float* __restrict__ qv, float* __restrict__ msum) {
  __shared__ __align__(16) u16 lsE[64][LDST];
  __shared__ __align__(16) u16 lsM[64][LDST];
  __shared__ float lsSig[64];
  const int tid = threadIdx.x, lane = tid & 63, wave = tid >> 6;
  const int lh = lane & 15, lq = lane >> 4;
  const int bv = blockIdx.x;
  const int bb = bv >> 7;

  float csum[4] = {0.f, 0.f, 0.f, 0.f};

  for (int hh = 0; hh < 2; ++hh) {
    if (tid < 64) lsSig[tid] = sigm(qv[(size_t)bv * NND + hh * 64 + tid]);
#pragma unroll
    for (int i = 0; i < 8; ++i) {
      int idx = tid + i * 256;
      int row = idx >> 5;
      int c8 = (idx & 31) << 3;
      *(u16x8*)(&lsM[row][c8]) =
          *(const u16x8*)(msgh + (size_t)(bb * NND + hh * 64 + row) * MSGD + c8);
    }
    f32x4 acc[4][4];
#pragma unroll
    for (int m = 0; m < 4; ++m)
#pragma unroll
      for (int t = 0; t < 4; ++t) acc[m][t] = zero4();

    for (int kc = 0; kc < 4; ++kc) {
#pragma unroll
      for (int i = 0; i < 16; ++i) {
        int idx = tid + i * 256;
        int row = idx >> 6;
        int c4 = (idx & 63) << 2;
        float4 f = *(const float4*)(edge + (size_t)(bv * NND + hh * 64 + row) * FEATD + kc * 256 + c4);
        u16x4 o; o[0] = f2bf(f.x); o[1] = f2bf(f.y); o[2] = f2bf(f.z); o[3] = f2bf(f.w);
        *(u16x4*)(&lsE[row][c4]) = o;
      }
      __syncthreads();
#pragma unroll
      for (int ks = 0; ks < 8; ++ks) {
        u16x8 afr[4];
#pragma unroll
        for (int m = 0; m < 4; ++m) afr[m] = *(const u16x8*)(&lsE[16 * m + lh][ks * 32 + lq * 8]);
        const int kg = kc * 256 + ks * 32 + lq * 8;
#pragma unroll
        for (int t = 0; t < 4; ++t) {
          int col = wave * 64 + t * 16 + lh;
          u16x8 bfr = *(const u16x8*)(Wcomb + (size_t)col * FEATD + kg);
#pragma unroll
          for (int m = 0; m < 4; ++m) acc[m][t] = mfma16(afr[m], bfr, acc[m][t]);
        }
      }
      __syncthreads();
    }
#pragma unroll
    for (int t = 0; t < 4; ++t) {
      int col = wave * 64 + t * 16 + lh;
      float bc = bcomb[col];
#pragma unroll
      for (int m = 0; m < 4; ++m)
#pragma unroll
        for (int j = 0; j < 4; ++j) {
          int row = 16 * m + 4 * lq + j;
          float m0 = fmaxf(acc[m][t][j] + bc + bf2f(lsM[row][col]), 0.f);
          csum[t] += lsSig[row] * m0;
        }
    }
    __syncthreads();
  }
#pragma unroll
  for (int off = 16; off < 64; off <<= 1)
#pragma unroll
    for (int t = 0; t < 4; ++t) csum[t] += __shfl_xor(csum[t], off, 64);
  if (lq == 0) {
#pragma unroll
    for (int t = 0; t < 4; ++t)
      msum[(size_t)bv * MSGD + wave * 64 + t * 16 + lh] = csum[t];
  }
}

// ---------------------------------------------------------------- GRU + labels
__global__ __launch_bounds__(256) void k_gru(const float* __restrict__ msum,
                                             const float* __restrict__ h32,
                                             const float* __restrict__ Wih, const float* __restrict__ bih,
                                             const float* __restrict__ Whh, const float* __restrict__ bhh,
                                             const float* __restrict__ Wr, const float* __restrict__ br,
                                             float* __restrict__ outlab) {
  __shared__ __align__(16) float sM[8][256];
  __shared__ __align__(16) float sH[8][256];
  __shared__ __align__(16) float sHn[8][256];
  const int tid = threadIdx.x;
  const int r0 = blockIdx.x * 8;
#pragma unroll
  for (int i = 0; i < 2; ++i) {
    int idx = tid + i * 256;
    int row = idx >> 6;
    int c = (idx & 63) << 2;
    *(float4*)(&sM[row][c]) = *(const float4*)(msum + (size_t)(r0 + row) * 256 + c);
    *(float4*)(&sH[row][c]) = *(const float4*)(h32 + (size_t)(r0 + row) * 256 + c);
  }
  __syncthreads();
  float gi[3][8], gh[3][8];
#pragma unroll
  for (int c = 0; c < 3; ++c) {
    float bi_ = bih[tid + 256 * c], bh_ = bhh[tid + 256 * c];
#pragma unroll
    for (int rr = 0; rr < 8; ++rr) { gi[c][rr] = bi_; gh[c][rr] = bh_; }
  }
  for (int k = 0; k < 256; k += 4) {
    float4 wi[3], wh[3];
#pragma unroll
    for (int c = 0; c < 3; ++c) {
      wi[c] = *(const float4*)(Wih + (size_t)(tid + 256 * c) * 256 + k);
      wh[c] = *(const float4*)(Whh + (size_t)(tid + 256 * c) * 256 + k);
    }
#pragma unroll
    for (int rr = 0; rr < 8; ++rr) {
      float4 ms = *(const float4*)(&sM[rr][k]);
      float4 hh = *(const float4*)(&sH[rr][k]);
#pragma unroll
      for (int c = 0; c < 3; ++c) {
        gi[c][rr] += wi[c].x * ms.x + wi[c].y * ms.y + wi[c].z * ms.z + wi[c].w * ms.w;
        gh[c][rr] += wh[c].x * hh.x + wh[c].y * hh.y + wh[c].z * hh.z + wh[c].w * hh.w;
      }
    }
  }
#pragma unroll
  for (int rr = 0; rr < 8; ++rr) {
    float r = sigm(gi[0][rr] + gh[0][rr]);
    float z = sigm(gi[1][rr] + gh[1][rr]);
    float n = tanhf(gi[2][rr] + r * gh[2][rr]);
    sHn[rr][tid] = (1.f - z) * n + z * sH[rr][tid];
  }
  __syncthreads();
  float lab[3][8];
  int cs[3]; bool has[3];
#pragma unroll
  for (int c = 0; c < 3; ++c) {
    cs[c] = tid + 256 * c;
    has[c] = cs[c] < CLSD;
    float b0 = has[c] ? br[cs[c]] : 0.f;
#pragma unroll
    for (int rr = 0; rr < 8; ++rr) lab[c][rr] = b0;
  }
  for (int k = 0; k < 256; k += 4) {
    float4 wr[3];
#pragma unroll
    for (int c = 0; c < 3; ++c) {
      if (has[c]) wr[c] = *(const float4*)(Wr + (size_t)cs[c] * 256 + k);
      else { wr[c].x = 0.f; wr[c].y = 0.f; wr[c].z = 0.f; wr[c].w = 0.f; }
    }
#pragma unroll
    for (int rr = 0; rr < 8; ++rr) {
      float4 hv = *(const float4*)(&sHn[rr][k]);
#pragma unroll
      for (int c = 0; c < 3; ++c)
        lab[c][rr] += wr[c].x * hv.x + wr[c].y * hv.y + wr[c].z * hv.z + wr[c].w * hv.w;
    }
  }
#pragma unroll
  for (int c = 0; c < 3; ++c) {
    if (has[c]) {
#pragma unroll
      for (int rr = 0; rr < 8; ++rr)
        outlab[(size_t)(r0 + rr) * CLSD + cs[c]] = lab[c][rr];
    }
  }
}

// ---------------------------------------------------------------- launch
extern "C" void kernel_launch(void* const* d_in, const int* in_sizes, int n_in,
                              void* d_out, int out_size, void* d_ws, size_t ws_size,
                              hipStream_t stream) {
  const float* edge = (const float*)d_in[0];
  const float* node = (const float*)d_in[1];
  const float* W_er = (const float*)d_in[6];
  const float* b_er = (const float*)d_in[7];
  const float* W_nr = (const float*)d_in[8];
  const float* b_nr = (const float*)d_in[9];
  const float* W_l1 = (const float*)d_in[10];
  const float* b_l1 = (const float*)d_in[11];
  const float* W_l2 = (const float*)d_in[12];
  const float* b_l2 = (const float*)d_in[13];
  const float* W_m  = (const float*)d_in[14];
  const float* b_m  = (const float*)d_in[15];
  const float* W_ih = (const float*)d_in[16];
  const float* b_ih = (const float*)d_in[17];
  const float* W_hh = (const float*)d_in[18];
  const float* b_hh = (const float*)d_in[19];
  const float* W_r  = (const float*)d_in[20];
  const float* b_r  = (const float*)d_in[21];

  char* ws = (char*)d_ws;
  size_t off = 0;
  auto alloc = [&](size_t bytes) -> void* {
    void* p = ws + off;
    off += (bytes + 511) & ~(size_t)511;
    return p;
  };
  u16* WerB     = (u16*)alloc((size_t)262144 * 2);
  u16* WmB      = (u16*)alloc((size_t)131072 * 2);
  u16* Wl1B     = (u16*)alloc((size_t)131072 * 2);
  u16* WcombB   = (u16*)alloc((size_t)262144 * 2);
  float* bcombF = (float*)alloc((size_t)256 * 4);
  u16* msghB    = (u16*)alloc((size_t)262144 * 2);
  float* h32    = (float*)alloc((size_t)262144 * 4);
  float* msum   = (float*)alloc((size_t)262144 * 4);
  u16* M0g      = (u16*)alloc((size_t)33554432 * 2);     // 64 MiB
  size_t off_m0 = off;
  u16* edgeB    = (u16*)alloc((size_t)134217728 * 2);    // 256 MiB
  size_t off_eb = off;
  const int tier = (ws_size >= off_eb) ? 0 : (ws_size >= off_m0 ? 1 : 2);

  float* out_pa  = (float*)d_out;
  float* out_lab = out_pa + 131072;

  k_cvt  <<<256,  256, 0, stream>>>(W_er, WerB, 262144);
  k_cvt  <<<128,  256, 0, stream>>>(W_m,  WmB,  131072);
  k_cvt  <<<128,  256, 0, stream>>>(W_l1, Wl1B, 131072);
  s1_hmsg<<<1024, 256, 0, stream>>>(node, W_nr, b_nr, W_m, h32, msghB);

  if (tier == 0) {
    k_cvt_edge<<<2048, 256, 0, stream>>>(edge, edgeB, (long)134217728);
    k_main_bf <<<2048, 512, 0, stream>>>(edgeB, WerB, WmB, Wl1B, b_er, b_m, b_l1, W_l2, b_l2,
                                         msghB, M0g, out_pa);
    k_msum_lite<<<1024, 256, 0, stream>>>(M0g, out_pa, msum);
  } else if (tier == 1) {
    k_main_f32<<<2048, 512, 0, stream>>>(edge, WerB, WmB, Wl1B, b_er, b_m, b_l1, W_l2, b_l2,
                                         msghB, M0g, out_pa);
    k_msum_lite<<<1024, 256, 0, stream>>>(M0g, out_pa, msum);
  } else {
    k_comb<<<1024, 256, 0, stream>>>(W_m, W_er, b_er, b_m, WcombB, bcombF);
    k_main_f32<<<2048, 512, 0, stream>>>(edge, WerB, WmB, Wl1B, b_er, b_m, b_l1, W_l2, b_l2,
                                         msghB, (u16*)nullptr, out_pa);
    k_msum2<<<1024, 256, 0, stream>>>(edge, WcombB, bcombF, msghB, out_pa, msum);
  }
  k_gru<<<128, 256, 0, stream>>>(msum, h32, W_ih, b_ih, W_hh, b_hh, W_r, b_r, out_lab);
}

// Round 8
// 715.273 us; speedup vs baseline: 1.2798x; 1.2798x over previous
//
#include <hip/hip_runtime.h>
#include <cstdint>
#include <cstddef>

#define NND   128
#define FEATD 1024
#define MSGD  256
#define LHD   512
#define CLSD  600
#define LDST  264   // padded LDS row stride (528B): quarter-wave b128 phases land 2-way = free (m136)

typedef __bf16 bf16_t;
typedef bf16_t bf16x8 __attribute__((ext_vector_type(8)));
typedef float  f32x4  __attribute__((ext_vector_type(4)));
typedef unsigned short u16;
typedef u16 u16x8 __attribute__((ext_vector_type(8)));
typedef u16 u16x4 __attribute__((ext_vector_type(4)));

static __device__ __forceinline__ float bf2f(u16 u) {
  union { unsigned u; float f; } x; x.u = ((unsigned)u) << 16; return x.f;
}
static __device__ __forceinline__ u16 f2bf(float f) {
  union { float f; unsigned u; } x; x.f = f;
  return (u16)((x.u + 0x7fffu + ((x.u >> 16) & 1u)) >> 16);  // RNE
}
static __device__ __forceinline__ f32x4 mfma16(u16x8 a, u16x8 b, f32x4 c) {
  return __builtin_amdgcn_mfma_f32_16x16x32_bf16(
      __builtin_bit_cast(bf16x8, a), __builtin_bit_cast(bf16x8, b), c, 0, 0, 0);
}
static __device__ __forceinline__ f32x4 zero4() {
  f32x4 v; v[0] = 0.f; v[1] = 0.f; v[2] = 0.f; v[3] = 0.f; return v;
}
static __device__ __forceinline__ float sigm(float x) { return 1.0f / (1.0f + expf(-x)); }

// ---------------------------------------------------------------- weight cvt f32->bf16
__global__ void k_cvt(const float* __restrict__ src, u16* __restrict__ dst, int n) {
  int i = (blockIdx.x * 256 + threadIdx.x) * 4;
  if (i + 3 < n) {
    float4 f = *(const float4*)(src + i);
    u16x4 o; o[0] = f2bf(f.x); o[1] = f2bf(f.y); o[2] = f2bf(f.z); o[3] = f2bf(f.w);
    *(u16x4*)(dst + i) = o;
  }
}

// ---------------------------------------------------------------- W_comb = W_me @ W_er (fallback tier only)
__global__ __launch_bounds__(256) void k_comb(const float* __restrict__ Wm,
                                              const float* __restrict__ Wer,
                                              const float* __restrict__ b_er,
                                              const float* __restrict__ b_m,
                                              u16* __restrict__ WcombB,
                                              float* __restrict__ bcomb) {
  const int m = blockIdx.x >> 2, ch = blockIdx.x & 3;
  const int d = ch * 256 + threadIdx.x;
  float s = 0.f;
  for (int k = 0; k < 256; ++k)
    s += Wm[(size_t)m * 512 + 256 + k] * Wer[(size_t)k * FEATD + d];
  WcombB[(size_t)m * FEATD + d] = f2bf(s);
  if (ch == 0 && threadIdx.x == 0) {
    float bb2 = b_m[m];
    for (int k = 0; k < 256; ++k) bb2 += Wm[(size_t)m * 512 + 256 + k] * b_er[k];
    bcomb[m] = bb2;
  }
}

// ---------------------------------------------------------------- S1: h (f32) + msg_h (bf16)
__global__ __launch_bounds__(256) void s1_hmsg(const float* __restrict__ node,
                                               const float* __restrict__ Wnr,
                                               const float* __restrict__ bnr,
                                               const float* __restrict__ Wm,
                                               float* __restrict__ h32,
                                               u16* __restrict__ msghB) {
  __shared__ float nrow[FEATD];
  __shared__ float hrow[MSGD];
  const int r = blockIdx.x;
  const int t = threadIdx.x;
  *(float4*)(&nrow[t * 4]) = *(const float4*)(node + (size_t)r * FEATD + t * 4);
  __syncthreads();
  float acc = bnr[t];
  for (int d = 0; d < FEATD; ++d) acc += nrow[d] * Wnr[(size_t)t * FEATD + d];
  h32[(size_t)r * MSGD + t] = acc;
  hrow[t] = acc;
  __syncthreads();
  float mh = 0.f;
  for (int k = 0; k < MSGD; ++k) mh += hrow[k] * Wm[(size_t)t * 2 * MSGD + k];
  msghB[(size_t)r * MSGD + t] = f2bf(mh);
}

// ---------------------------------------------------------------- fused main kernel (256 thr = 4 waves, fat regs)
// Phase0: e = edge@Wer^T + b_er via 16 BK=64 steps, depth-2 reg prefetch, 1 barrier/step.
// A: sig1; B: M0 (-> M0g) and m1 = sig1*M0 -> lsM; C: pred_adj2 scattered transposed (f32).
__global__ __launch_bounds__(256, 2) void k_main(
    const float* __restrict__ edge, const u16* __restrict__ Wer, const u16* __restrict__ Wm,
    const u16* __restrict__ Wl1, const float* __restrict__ b_er, const float* __restrict__ b_m,
    const float* __restrict__ b_l1, const float* __restrict__ W_l2, const float* __restrict__ b_l2,
    const u16* __restrict__ msgh, u16* __restrict__ M0g, float* __restrict__ pa_out) {
  __shared__ __align__(16) u16 lsE[64][LDST];   // phase0: A-chunk dbuf in cols [0,64)|[64,128); then e
  __shared__ __align__(16) u16 lsM[64][LDST];
  __shared__ float lsPA[4][64];
  __shared__ float lsSig[64];

  const int tid = threadIdx.x, lane = tid & 63, wave = tid >> 6;  // 4 waves
  const int lh = lane & 15, lq = lane >> 4;
  const int base = blockIdx.x * 64;
  const int bb = base >> 14, vv = (base >> 7) & 127, w0 = base & 127;

  f32x4 acc[4][4];
#pragma unroll
  for (int m = 0; m < 4; ++m)
#pragma unroll
    for (int t = 0; t < 4; ++t) acc[m][t] = zero4();

  // ---------------- Phase 0: 16 K-steps of BK=64, depth-2 pipeline ----------------
  const int srow = tid >> 2;            // 0..63
  const int scq  = (tid & 3) * 16;      // 0,16,32,48
  const float* esrc = edge + (size_t)(base + srow) * FEATD + scq;
  float4 lda[4], ldb[4];

  auto LOADS_A = [&](int s) {
#pragma unroll
    for (int i = 0; i < 4; ++i) lda[i] = *(const float4*)(esrc + s * 64 + i * 4);
  };
  auto LOADS_B = [&](int s) {
#pragma unroll
    for (int i = 0; i < 4; ++i) ldb[i] = *(const float4*)(esrc + s * 64 + i * 4);
  };
  auto WRITES = [&](const float4* ld, int slot) {
    u16* wp = &lsE[srow][slot * 64 + scq];
    u16x8 o0, o1;
    o0[0] = f2bf(ld[0].x); o0[1] = f2bf(ld[0].y); o0[2] = f2bf(ld[0].z); o0[3] = f2bf(ld[0].w);
    o0[4] = f2bf(ld[1].x); o0[5] = f2bf(ld[1].y); o0[6] = f2bf(ld[1].z); o0[7] = f2bf(ld[1].w);
    o1[0] = f2bf(ld[2].x); o1[1] = f2bf(ld[2].y); o1[2] = f2bf(ld[2].z); o1[3] = f2bf(ld[2].w);
    o1[4] = f2bf(ld[3].x); o1[5] = f2bf(ld[3].y); o1[6] = f2bf(ld[3].z); o1[7] = f2bf(ld[3].w);
    *(u16x8*)wp = o0;
    *(u16x8*)(wp + 8) = o1;
  };
  auto MSTEP = [&](int sk, int slot) {
#pragma unroll
    for (int ks = 0; ks < 2; ++ks) {
      u16x8 afr[4];
#pragma unroll
      for (int m = 0; m < 4; ++m)
        afr[m] = *(const u16x8*)(&lsE[16 * m + lh][slot * 64 + ks * 32 + lq * 8]);
      const int kg = sk * 64 + ks * 32 + lq * 8;
#pragma unroll
      for (int t = 0; t < 4; ++t) {
        int col = wave * 64 + t * 16 + lh;
        u16x8 bfr = *(const u16x8*)(Wer + (size_t)col * FEATD + kg);
#pragma unroll
        for (int m = 0; m < 4; ++m) acc[m][t] = mfma16(afr[m], bfr, acc[m][t]);
      }
    }
  };

  LOADS_A(0);
  LOADS_B(1);
  for (int s2 = 0; s2 < 16; s2 += 2) {
    // even step (slot 0, regs lda)
    WRITES(lda, 0);
    if (s2 + 2 < 16) LOADS_A(s2 + 2);
    __syncthreads();
    MSTEP(s2, 0);
    // odd step (slot 1, regs ldb)
    WRITES(ldb, 1);
    if (s2 + 3 < 16) LOADS_B(s2 + 3);
    __syncthreads();
    MSTEP(s2 + 1, 1);
  }
  __syncthreads();   // all MFMA(15) reads done before e overwrites lsE
#pragma unroll
  for (int t = 0; t < 4; ++t) {
    int col = wave * 64 + t * 16 + lh;
    float be = b_er[col];
#pragma unroll
    for (int m = 0; m < 4; ++m)
#pragma unroll
      for (int j = 0; j < 4; ++j)
        lsE[16 * m + 4 * lq + j][col] = f2bf(acc[m][t][j] + be);
  }
  __syncthreads();

  // ---------------- Phase A: sig1 ----------------
  float prow[4][4];
#pragma unroll
  for (int m = 0; m < 4; ++m)
#pragma unroll
    for (int j = 0; j < 4; ++j) prow[m][j] = 0.f;
#pragma unroll
  for (int np = 0; np < 2; ++np) {
#pragma unroll
    for (int m = 0; m < 4; ++m)
#pragma unroll
      for (int t = 0; t < 4; ++t) acc[m][t] = zero4();
#pragma unroll
    for (int ks = 0; ks < 8; ++ks) {
      u16x8 afr[4];
#pragma unroll
      for (int m = 0; m < 4; ++m) afr[m] = *(const u16x8*)(&lsE[16 * m + lh][ks * 32 + lq * 8]);
      const int kg = ks * 32 + lq * 8;
#pragma unroll
      for (int t = 0; t < 4; ++t) {
        int col = wave * 128 + np * 64 + t * 16 + lh;
        u16x8 bfr = *(const u16x8*)(Wl1 + (size_t)col * MSGD + kg);
#pragma unroll
        for (int m = 0; m < 4; ++m) acc[m][t] = mfma16(afr[m], bfr, acc[m][t]);
      }
    }
#pragma unroll
    for (int t = 0; t < 4; ++t) {
      int col = wave * 128 + np * 64 + t * 16 + lh;
      float bl = b_l1[col], wl = W_l2[col];
#pragma unroll
      for (int m = 0; m < 4; ++m)
#pragma unroll
        for (int j = 0; j < 4; ++j) prow[m][j] += fmaxf(acc[m][t][j] + bl, 0.f) * wl;
    }
  }
#pragma unroll
  for (int off = 1; off < 16; off <<= 1)
#pragma unroll
    for (int m = 0; m < 4; ++m)
#pragma unroll
      for (int j = 0; j < 4; ++j) prow[m][j] += __shfl_xor(prow[m][j], off, 64);
  if (lh == 0) {
#pragma unroll
    for (int m = 0; m < 4; ++m)
#pragma unroll
      for (int j = 0; j < 4; ++j) lsPA[wave][16 * m + 4 * lq + j] = prow[m][j];
  }
  __syncthreads();
  if (tid < 64) {
    float pa1 = lsPA[0][tid] + lsPA[1][tid] + lsPA[2][tid] + lsPA[3][tid] + b_l2[0];
    lsSig[tid] = sigm(pa1);
  }
  // stage msg_h rows [w0, w0+64) into lsM
#pragma unroll
  for (int i = 0; i < 8; ++i) {
    int idx = tid + i * 256;
    int row = idx >> 5;
    int c8 = (idx & 31) << 3;
    *(u16x8*)(&lsM[row][c8]) =
        *(const u16x8*)(msgh + (size_t)(bb * NND + w0 + row) * MSGD + c8);
  }
  __syncthreads();

  // ---------------- Phase B: M0 = relu(msg_h + e@Wme^T + b_m) ----------------
#pragma unroll
  for (int m = 0; m < 4; ++m)
#pragma unroll
    for (int t = 0; t < 4; ++t) acc[m][t] = zero4();
#pragma unroll
  for (int ks = 0; ks < 8; ++ks) {
    u16x8 afr[4];
#pragma unroll
    for (int m = 0; m < 4; ++m) afr[m] = *(const u16x8*)(&lsE[16 * m + lh][ks * 32 + lq * 8]);
    const int kg = ks * 32 + lq * 8;
#pragma unroll
    for (int t = 0; t < 4; ++t) {
      int col = wave * 64 + t * 16 + lh;
      u16x8 bfr = *(const u16x8*)(Wm + (size_t)col * 512 + 256 + kg);  // W_me = right half
#pragma unroll
      for (int m = 0; m < 4; ++m) acc[m][t] = mfma16(afr[m], bfr, acc[m][t]);
    }
  }
#pragma unroll
  for (int t = 0; t < 4; ++t) {
    int col = wave * 64 + t * 16 + lh;
    float bm = b_m[col];
#pragma unroll
    for (int m = 0; m < 4; ++m)
#pragma unroll
      for (int j = 0; j < 4; ++j) {
        int row = 16 * m + 4 * lq + j;
        float mh = bf2f(lsM[row][col]);
        lsM[row][col] = f2bf(fmaxf(acc[m][t][j] + bm + mh, 0.f));
      }
  }
  __syncthreads();
  // M0 -> global; prescale lsM in place: m1 = sig1 * M0
#pragma unroll
  for (int i = 0; i < 8; ++i) {
    int idx = tid + i * 256;
    int row = idx >> 5;
    int c8 = (idx & 31) << 3;
    u16x8 m0v = *(const u16x8*)(&lsM[row][c8]);
    if (M0g) *(u16x8*)(M0g + (size_t)(base + row) * MSGD + c8) = m0v;
    float s = lsSig[row];
    u16x8 sc;
#pragma unroll
    for (int j = 0; j < 8; ++j) sc[j] = f2bf(bf2f(m0v[j]) * s);
    *(u16x8*)(&lsM[row][c8]) = sc;
  }
  __syncthreads();

  // ---------------- Phase C: pred_adj2 (scatter transposed, f32) ----------------
#pragma unroll
  for (int m = 0; m < 4; ++m)
#pragma unroll
    for (int j = 0; j < 4; ++j) prow[m][j] = 0.f;
#pragma unroll
  for (int np = 0; np < 2; ++np) {
#pragma unroll
    for (int m = 0; m < 4; ++m)
#pragma unroll
      for (int t = 0; t < 4; ++t) acc[m][t] = zero4();
#pragma unroll
    for (int ks = 0; ks < 8; ++ks) {
      u16x8 afr[4];
#pragma unroll
      for (int m = 0; m < 4; ++m) afr[m] = *(const u16x8*)(&lsM[16 * m + lh][ks * 32 + lq * 8]);
      const int kg = ks * 32 + lq * 8;
#pragma unroll
      for (int t = 0; t < 4; ++t) {
        int col = wave * 128 + np * 64 + t * 16 + lh;
        u16x8 bfr = *(const u16x8*)(Wl1 + (size_t)col * MSGD + kg);
#pragma unroll
        for (int m = 0; m < 4; ++m) acc[m][t] = mfma16(afr[m], bfr, acc[m][t]);
      }
    }
#pragma unroll
    for (int t = 0; t < 4; ++t) {
      int col = wave * 128 + np * 64 + t * 16 + lh;
      float bl = b_l1[col], wl = W_l2[col];
#pragma unroll
      for (int m = 0; m < 4; ++m)
#pragma unroll
        for (int j = 0; j < 4; ++j) prow[m][j] += fmaxf(acc[m][t][j] + bl, 0.f) * wl;
    }
  }
#pragma unroll
  for (int off = 1; off < 16; off <<= 1)
#pragma unroll
    for (int m = 0; m < 4; ++m)
#pragma unroll
      for (int j = 0; j < 4; ++j) prow[m][j] += __shfl_xor(prow[m][j], off, 64);
  if (lh == 0) {
#pragma unroll
    for (int m = 0; m < 4; ++m)
#pragma unroll
      for (int j = 0; j < 4; ++j) lsPA[wave][16 * m + 4 * lq + j] = prow[m][j];
  }
  __syncthreads();
  if (tid < 64) {
    float q = lsPA[0][tid] + lsPA[1][tid] + lsPA[2][tid] + lsPA[3][tid] + b_l2[0];
    size_t o = ((size_t)bb * NND + (w0 + tid)) * NND + vv;  // pred_adj2[b][w0+tid][vv]
    pa_out[o] = q;
  }
}

// ---------------------------------------------------------------- m_sum from stored M0
__global__ __launch_bounds__(256) void k_msum_lite(const u16* __restrict__ M0g,
                                                   const float* __restrict__ qv,
                                                   float* __restrict__ msum) {
  __shared__ float sig[128];
  const int bv = blockIdx.x, tid = threadIdx.x;
  if (tid < 128) sig[tid] = sigm(qv[(size_t)bv * NND + tid]);
  __syncthreads();
  const u16* p = M0g + (size_t)bv * NND * MSGD + tid;
  float a = 0.f;
#pragma unroll 8
  for (int w = 0; w < 128; ++w) a += sig[w] * bf2f(p[(size_t)w * MSGD]);
  msum[(size_t)bv * MSGD + tid] = a;
}

// ---------------------------------------------------------------- fallback m_sum: recompute via W_comb (f32 edge)
__global__ __launch_bounds__(256, 2) void k_msum2(
    const float* __restrict__ edge, const u16* __restrict__ Wcomb,
    const float* __restrict__ bcomb, const u16* __restrict__ msgh,
    const float* __restrict__ qv, float* __restrict__ msum) {
  __shared__ __align__(16) u16 lsE[64][LDST];
  __shared__ __align__(16) u16 lsM[64][LDST];
  __shared__ float lsSig[64];
  const int tid = threadIdx.x, lane = tid & 63, wave = tid >> 6;
  const int lh = lane & 15, lq = lane >> 4;
  const int bv = blockIdx.x;
  const int bb = bv >> 7;

  float csum[4] = {0.f, 0.f, 0.f, 0.f};

  for (int hh = 0; hh < 2; ++hh) {
    if (tid < 64) lsSig[tid] = sigm(qv[(size_t)bv * NND + hh * 64 + tid]);
#pragma unroll
    for (int i = 0; i < 8; ++i) {
      int idx = tid + i * 256;
      int row = idx >> 5;
      int c8 = (idx & 31) << 3;
      *(u16x8*)(&lsM[row][c8]) =
          *(const u16x8*)(msgh + (size_t)(bb * NND + hh * 64 + row) * MSGD + c8);
    }
    f32x4 acc[4][4];
#pragma unroll
    for (int m = 0; m < 4; ++m)
#pragma unroll
      for (int t = 0; t < 4; ++t) acc[m][t] = zero4();

    for (int kc = 0; kc < 4; ++kc) {
#pragma unroll
      for (int i = 0; i < 16; ++i) {
        int idx = tid + i * 256;
        int row = idx >> 6;
        int c4 = (idx & 63) << 2;
        float4 f = *(const float4*)(edge + (size_t)(bv * NND + hh * 64 + row) * FEATD + kc * 256 + c4);
        u16x4 o; o[0] = f2bf(f.x); o[1] = f2bf(f.y); o[2] = f2bf(f.z); o[3] = f2bf(f.w);
        *(u16x4*)(&lsE[row][c4]) = o;
      }
      __syncthreads();
#pragma unroll
      for (int ks = 0; ks < 8; ++ks) {
        u16x8 afr[4];
#pragma unroll
        for (int m = 0; m < 4; ++m) afr[m] = *(const u16x8*)(&lsE[16 * m + lh][ks * 32 + lq * 8]);
        const int kg = kc * 256 + ks * 32 + lq * 8;
#pragma unroll
        for (int t = 0; t < 4; ++t) {
          int col = wave * 64 + t * 16 + lh;
          u16x8 bfr = *(const u16x8*)(Wcomb + (size_t)col * FEATD + kg);
#pragma unroll
          for (int m = 0; m < 4; ++m) acc[m][t] = mfma16(afr[m], bfr, acc[m][t]);
        }
      }
      __syncthreads();
    }
#pragma unroll
    for (int t = 0; t < 4; ++t) {
      int col = wave * 64 + t * 16 + lh;
      float bc = bcomb[col];
#pragma unroll
      for (int m = 0; m < 4; ++m)
#pragma unroll
        for (int j = 0; j < 4; ++j) {
          int row = 16 * m + 4 * lq + j;
          float m0 = fmaxf(acc[m][t][j] + bc + bf2f(lsM[row][col]), 0.f);
          csum[t] += lsSig[row] * m0;
        }
    }
    __syncthreads();
  }
#pragma unroll
  for (int off = 16; off < 64; off <<= 1)
#pragma unroll
    for (int t = 0; t < 4; ++t) csum[t] += __shfl_xor(csum[t], off, 64);
  if (lq == 0) {
#pragma unroll
    for (int t = 0; t < 4; ++t)
      msum[(size_t)bv * MSGD + wave * 64 + t * 16 + lh] = csum[t];
  }
}

// ---------------------------------------------------------------- GRU + labels
__global__ __launch_bounds__(256) void k_gru(const float* __restrict__ msum,
                                             const float* __restrict__ h32,
                                             const float* __restrict__ Wih, const float* __restrict__ bih,
                                             const float* __restrict__ Whh, const float* __restrict__ bhh,
                                             const float* __restrict__ Wr, const float* __restrict__ br,
                                             float* __restrict__ outlab) {
  __shared__ __align__(16) float sM[8][256];
  __shared__ __align__(16) float sH[8][256];
  __shared__ __align__(16) float sHn[8][256];
  const int tid = threadIdx.x;
  const int r0 = blockIdx.x * 8;
#pragma unroll
  for (int i = 0; i < 2; ++i) {
    int idx = tid + i * 256;
    int row = idx >> 6;
    int c = (idx & 63) << 2;
    *(float4*)(&sM[row][c]) = *(const float4*)(msum + (size_t)(r0 + row) * 256 + c);
    *(float4*)(&sH[row][c]) = *(const float4*)(h32 + (size_t)(r0 + row) * 256 + c);
  }
  __syncthreads();
  float gi[3][8], gh[3][8];
#pragma unroll
  for (int c = 0; c < 3; ++c) {
    float bi_ = bih[tid + 256 * c], bh_ = bhh[tid + 256 * c];
#pragma unroll
    for (int rr = 0; rr < 8; ++rr) { gi[c][rr] = bi_; gh[c][rr] = bh_; }
  }
  for (int k = 0; k < 256; k += 4) {
    float4 wi[3], wh[3];
#pragma unroll
    for (int c = 0; c < 3; ++c) {
      wi[c] = *(const float4*)(Wih + (size_t)(tid + 256 * c) * 256 + k);
      wh[c] = *(const float4*)(Whh + (size_t)(tid + 256 * c) * 256 + k);
    }
#pragma unroll
    for (int rr = 0; rr < 8; ++rr) {
      float4 ms = *(const float4*)(&sM[rr][k]);
      float4 hh = *(const float4*)(&sH[rr][k]);
#pragma unroll
      for (int c = 0; c < 3; ++c) {
        gi[c][rr] += wi[c].x * ms.x + wi[c].y * ms.y + wi[c].z * ms.z + wi[c].w * ms.w;
        gh[c][rr] += wh[c].x * hh.x + wh[c].y * hh.y + wh[c].z * hh.z + wh[c].w * hh.w;
      }
    }
  }
#pragma unroll
  for (int rr = 0; rr < 8; ++rr) {
    float r = sigm(gi[0][rr] + gh[0][rr]);
    float z = sigm(gi[1][rr] + gh[1][rr]);
    float n = tanhf(gi[2][rr] + r * gh[2][rr]);
    sHn[rr][tid] = (1.f - z) * n + z * sH[rr][tid];
  }
  __syncthreads();
  float lab[3][8];
  int cs[3]; bool has[3];
#pragma unroll
  for (int c = 0; c < 3; ++c) {
    cs[c] = tid + 256 * c;
    has[c] = cs[c] < CLSD;
    float b0 = has[c] ? br[cs[c]] : 0.f;
#pragma unroll
    for (int rr = 0; rr < 8; ++rr) lab[c][rr] = b0;
  }
  for (int k = 0; k < 256; k += 4) {
    float4 wr[3];
#pragma unroll
    for (int c = 0; c < 3; ++c) {
      if (has[c]) wr[c] = *(const float4*)(Wr + (size_t)cs[c] * 256 + k);
      else { wr[c].x = 0.f; wr[c].y = 0.f; wr[c].z = 0.f; wr[c].w = 0.f; }
    }
#pragma unroll
    for (int rr = 0; rr < 8; ++rr) {
      float4 hv = *(const float4*)(&sHn[rr][k]);
#pragma unroll
      for (int c = 0; c < 3; ++c)
        lab[c][rr] += wr[c].x * hv.x + wr[c].y * hv.y + wr[c].z * hv.z + wr[c].w * hv.w;
    }
  }
#pragma unroll
  for (int c = 0; c < 3; ++c) {
    if (has[c]) {
#pragma unroll
      for (int rr = 0; rr < 8; ++rr)
        outlab[(size_t)(r0 + rr) * CLSD + cs[c]] = lab[c][rr];
    }
  }
}

// ---------------------------------------------------------------- launch
extern "C" void kernel_launch(void* const* d_in, const int* in_sizes, int n_in,
                              void* d_out, int out_size, void* d_ws, size_t ws_size,
                              hipStream_t stream) {
  const float* edge = (const float*)d_in[0];
  const float* node = (const float*)d_in[1];
  const float* W_er = (const float*)d_in[6];
  const float* b_er = (const float*)d_in[7];
  const float* W_nr = (const float*)d_in[8];
  const float* b_nr = (const float*)d_in[9];
  const float* W_l1 = (const float*)d_in[10];
  const float* b_l1 = (const float*)d_in[11];
  const float* W_l2 = (const float*)d_in[12];
  const float* b_l2 = (const float*)d_in[13];
  const float* W_m  = (const float*)d_in[14];
  const float* b_m  = (const float*)d_in[15];
  const float* W_ih = (const float*)d_in[16];
  const float* b_ih = (const float*)d_in[17];
  const float* W_hh = (const float*)d_in[18];
  const float* b_hh = (const float*)d_in[19];
  const float* W_r  = (const float*)d_in[20];
  const float* b_r  = (const float*)d_in[21];

  char* ws = (char*)d_ws;
  size_t off = 0;
  auto alloc = [&](size_t bytes) -> void* {
    void* p = ws + off;
    off += (bytes + 511) & ~(size_t)511;
    return p;
  };
  u16* WerB     = (u16*)alloc((size_t)262144 * 2);
  u16* WmB      = (u16*)alloc((size_t)131072 * 2);
  u16* Wl1B     = (u16*)alloc((size_t)131072 * 2);
  u16* WcombB   = (u16*)alloc((size_t)262144 * 2);
  float* bcombF = (float*)alloc((size_t)256 * 4);
  u16* msghB    = (u16*)alloc((size_t)262144 * 2);
  float* h32    = (float*)alloc((size_t)262144 * 4);
  float* msum   = (float*)alloc((size_t)262144 * 4);
  u16* M0g      = (u16*)alloc((size_t)33554432 * 2);   // 64 MiB
  size_t off_m0 = off;
  const bool fast = (ws_size >= off_m0);               // ws proved >= 330 MB in R7, but keep guard
  u16* M0arg = fast ? M0g : (u16*)nullptr;

  float* out_pa  = (float*)d_out;
  float* out_lab = out_pa + 131072;

  k_cvt  <<<256,  256, 0, stream>>>(W_er, WerB, 262144);
  k_cvt  <<<128,  256, 0, stream>>>(W_m,  WmB,  131072);
  k_cvt  <<<128,  256, 0, stream>>>(W_l1, Wl1B, 131072);
  s1_hmsg<<<1024, 256, 0, stream>>>(node, W_nr, b_nr, W_m, h32, msghB);
  if (!fast)
    k_comb<<<1024, 256, 0, stream>>>(W_m, W_er, b_er, b_m, WcombB, bcombF);

  k_main<<<2048, 256, 0, stream>>>(edge, WerB, WmB, Wl1B, b_er, b_m, b_l1, W_l2, b_l2,
                                   msghB, M0arg, out_pa);
  if (fast)
    k_msum_lite<<<1024, 256, 0, stream>>>(M0g, out_pa, msum);
  else
    k_msum2<<<1024, 256, 0, stream>>>(edge, WcombB, bcombF, msghB, out_pa, msum);
  k_gru<<<128, 256, 0, stream>>>(msum, h32, W_ih, b_ih, W_hh, b_hh, W_r, b_r, out_lab);
}